// Round 5
// baseline (215.516 us; speedup 1.0000x reference)
//
#include <hip/hip_runtime.h>
#include <hip/hip_bf16.h>

#define DIM 64
#define HEADS 4
#define HD 256   // HEADS*DIM

// ---------------------------------------------------------------------------
// helpers
// ---------------------------------------------------------------------------
template<int CTRL>
__device__ __forceinline__ float dpp_rot(float x) {
    return __int_as_float(__builtin_amdgcn_update_dpp(
        0, __float_as_int(x), CTRL, 0xF, 0xF, true));
}
// sum across each 16-lane row via rotational Hillis-Steele (pure VALU DPP)
__device__ __forceinline__ float reduce16(float x) {
    x += dpp_rot<0x121>(x);   // row_ror:1
    x += dpp_rot<0x122>(x);   // row_ror:2
    x += dpp_rot<0x124>(x);   // row_ror:4
    x += dpp_rot<0x128>(x);   // row_ror:8
    return x;
}
__device__ __forceinline__ int wave_isum(int x) {
    #pragma unroll
    for (int off = 32; off; off >>= 1) x += __shfl_xor(x, off, 64);
    return x;
}
__device__ __forceinline__ unsigned short f2bf(float f) {
    unsigned u = __float_as_uint(f);
    unsigned r = (u + 0x7FFFu + ((u >> 16) & 1u)) >> 16;   // RNE
    return (unsigned short)r;
}
__device__ __forceinline__ float bf2f(unsigned short u) {
    return __uint_as_float((unsigned)u << 16);
}

// ---------------------------------------------------------------------------
// K1: per-dst histogram + weighted in-degree (counts/deg pre-zeroed by memset)
// ---------------------------------------------------------------------------
__global__ void edge_count(const int* __restrict__ edges, const float* __restrict__ ew,
                           int* counts, float* deg, int nE) {
    int e = blockIdx.x * blockDim.x + threadIdx.x;
    if (e < nE) {
        int dst = edges[nE + e];           // edges[1][e]
        atomicAdd(&counts[dst], 1);
        atomicAdd(&deg[dst], ew[e]);
    }
}

// ---------------------------------------------------------------------------
// K2a: per-block sums of counts
// ---------------------------------------------------------------------------
__global__ __launch_bounds__(256) void block_sums(const int* __restrict__ counts,
                                                  int* bsum, int n) {
    __shared__ int w4[4];
    int tid = threadIdx.x;
    int i = blockIdx.x * 256 + tid;
    int v = (i < n) ? counts[i] : 0;
    v = wave_isum(v);
    if ((tid & 63) == 0) w4[tid >> 6] = v;
    __syncthreads();
    if (tid == 0) bsum[blockIdx.x] = w4[0] + w4[1] + w4[2] + w4[3];
}

// ---------------------------------------------------------------------------
// K2b: per-block exclusive scan + block offset -> rowptr/cursor; dinv
// requires gridDim.x <= 256
// ---------------------------------------------------------------------------
__global__ __launch_bounds__(256) void scan_apply(const int* __restrict__ counts,
                                                  const int* __restrict__ bsum,
                                                  const float* __restrict__ deg,
                                                  int* rowptr, int* cursor, float* dinv,
                                                  int n, int nE) {
    __shared__ int sdata[256];
    __shared__ int w4[4];
    int tid = threadIdx.x, bid = blockIdx.x;
    int i = bid * 256 + tid;
    int pv = (tid < bid) ? bsum[tid] : 0;
    pv = wave_isum(pv);
    if ((tid & 63) == 0) w4[tid >> 6] = pv;
    __syncthreads();
    int boff = w4[0] + w4[1] + w4[2] + w4[3];
    int vv = (i < n) ? counts[i] : 0;
    sdata[tid] = vv;
    __syncthreads();
    #pragma unroll
    for (int off = 1; off < 256; off <<= 1) {
        int t = (tid >= off) ? sdata[tid - off] : 0;
        __syncthreads();
        sdata[tid] += t;
        __syncthreads();
    }
    int incl = sdata[tid];
    if (i < n) {
        int rp = boff + incl - vv;         // exclusive
        rowptr[i] = rp;
        cursor[i] = rp;
        dinv[i] = rsqrtf(deg[i] + 1.0f);   // +1 = self-loop weight
        if (i == n - 1) rowptr[n] = nE;
    }
}

// ---------------------------------------------------------------------------
// K3: scatter edges into CSR (grouped by dst), packed (src, weight) 8B record
// ---------------------------------------------------------------------------
__global__ void edge_scatter(const int* __restrict__ edges, const float* __restrict__ ew,
                             int* cursor, int2* __restrict__ csr, int nE) {
    int e = blockIdx.x * blockDim.x + threadIdx.x;
    if (e < nE) {
        int dst = edges[nE + e];
        int src = edges[e];
        int p = atomicAdd(&cursor[dst], 1);
        int2 rec;
        rec.x = src;
        rec.y = __float_as_int(ew[e]);
        csr[p] = rec;
    }
}

// ---------------------------------------------------------------------------
// K4: xws = dinv[row] * (f_mole @ gcn_w), stored bf16.  64-col GEMM.
// ---------------------------------------------------------------------------
__global__ __launch_bounds__(256) void gemm_xw(const float* __restrict__ A,
                                               const float* __restrict__ W,
                                               const float* __restrict__ dinv,
                                               unsigned short* __restrict__ out,
                                               int n) {
    __shared__ float As[64][68];   // As[k][r]
    __shared__ float Bs[64][68];   // Bs[k][c]
    int row0 = blockIdx.x * 64;
    int tid = threadIdx.x;
    #pragma unroll
    for (int it = 0; it < 4; ++it) {
        int r  = (tid >> 4) + it * 16;
        int c4 = (tid & 15) * 4;
        float4 val = make_float4(0.f, 0.f, 0.f, 0.f);
        if (row0 + r < n)
            val = *reinterpret_cast<const float4*>(A + (size_t)(row0 + r) * DIM + c4);
        As[c4 + 0][r] = val.x;
        As[c4 + 1][r] = val.y;
        As[c4 + 2][r] = val.z;
        As[c4 + 3][r] = val.w;
        *reinterpret_cast<float4*>(&Bs[r][c4]) =
            *reinterpret_cast<const float4*>(W + (size_t)r * DIM + c4);
    }
    __syncthreads();
    int r0 = (tid >> 4) * 4;
    int c0 = (tid & 15) * 4;
    float acc[4][4] = {};
    #pragma unroll 8
    for (int kk = 0; kk < 64; ++kk) {
        float4 av = *reinterpret_cast<const float4*>(&As[kk][r0]);
        float4 bv = *reinterpret_cast<const float4*>(&Bs[kk][c0]);
        float a_[4] = {av.x, av.y, av.z, av.w};
        float b_[4] = {bv.x, bv.y, bv.z, bv.w};
        #pragma unroll
        for (int i = 0; i < 4; ++i)
            #pragma unroll
            for (int j = 0; j < 4; ++j)
                acc[i][j] += a_[i] * b_[j];
    }
    #pragma unroll
    for (int i = 0; i < 4; ++i) {
        int r = row0 + r0 + i;
        if (r >= n) continue;
        float s = dinv[r];
        ushort4 u;
        u.x = f2bf(s * acc[i][0]); u.y = f2bf(s * acc[i][1]);
        u.z = f2bf(s * acc[i][2]); u.w = f2bf(s * acc[i][3]);
        *reinterpret_cast<ushort4*>(out + (size_t)r * DIM + c0) = u;
    }
}

// ---------------------------------------------------------------------------
// K5: GCN aggregation.  One wave per node.
// lane = (edge-slot = lane>>4, 4-chan group = lane&15); up to 16 edges in
// flight.  xws is bf16, pre-scaled by dinv[src]; weight lives in csr rec.
// f_gcn = relu( dinv[i]*(xws[i] + sum_e w*xws[src]) + b )
// ---------------------------------------------------------------------------
__global__ __launch_bounds__(256) void gcn_agg(const unsigned short* __restrict__ xws,
                                               const int* __restrict__ rowptr,
                                               const int2* __restrict__ csr,
                                               const float* __restrict__ dinv,
                                               const float* __restrict__ gcn_b,
                                               float* __restrict__ f_gcn, int n) {
    int wave = threadIdx.x >> 6;
    int lane = threadIdx.x & 63;
    int i = blockIdx.x * 4 + wave;
    if (i >= n) return;
    int eo = lane >> 4;
    int cg = lane & 15;

    float4 acc = make_float4(0.f, 0.f, 0.f, 0.f);
    int e0 = rowptr[i], e1 = rowptr[i + 1];
    int eb = e0;
    for (; eb + 16 <= e1; eb += 16) {
        int2 p[4];
        #pragma unroll
        for (int j = 0; j < 4; ++j) p[j] = csr[eb + 4 * j + eo];
        ushort4 x[4];
        #pragma unroll
        for (int j = 0; j < 4; ++j)
            x[j] = *reinterpret_cast<const ushort4*>(xws + (size_t)p[j].x * DIM + cg * 4);
        #pragma unroll
        for (int j = 0; j < 4; ++j) {
            float c = __int_as_float(p[j].y);
            acc.x += c * bf2f(x[j].x); acc.y += c * bf2f(x[j].y);
            acc.z += c * bf2f(x[j].z); acc.w += c * bf2f(x[j].w);
        }
    }
    for (int e = eb + eo; e < e1; e += 4) {
        int2 p = csr[e];
        float c = __int_as_float(p.y);
        ushort4 x4 = *reinterpret_cast<const ushort4*>(xws + (size_t)p.x * DIM + cg * 4);
        acc.x += c * bf2f(x4.x); acc.y += c * bf2f(x4.y);
        acc.z += c * bf2f(x4.z); acc.w += c * bf2f(x4.w);
    }
    // sum the 4 edge-slots (cross-quarter)
    acc.x += __shfl_xor(acc.x, 16, 64); acc.x += __shfl_xor(acc.x, 32, 64);
    acc.y += __shfl_xor(acc.y, 16, 64); acc.y += __shfl_xor(acc.y, 32, 64);
    acc.z += __shfl_xor(acc.z, 16, 64); acc.z += __shfl_xor(acc.z, 32, 64);
    acc.w += __shfl_xor(acc.w, 16, 64); acc.w += __shfl_xor(acc.w, 32, 64);

    float di = dinv[i];
    ushort4 xs = *reinterpret_cast<const ushort4*>(xws + (size_t)i * DIM + cg * 4);
    const float* b = gcn_b + cg * 4;
    float4 r;
    r.x = fmaxf(di * (acc.x + bf2f(xs.x)) + b[0], 0.f);
    r.y = fmaxf(di * (acc.y + bf2f(xs.y)) + b[1], 0.f);
    r.z = fmaxf(di * (acc.z + bf2f(xs.z)) + b[2], 0.f);
    r.w = fmaxf(di * (acc.w + bf2f(xs.w)) + b[3], 0.f);
    if (eo == 0)
        *reinterpret_cast<float4*>(f_gcn + (size_t)i * DIM + cg * 4) = r;
}

// ---------------------------------------------------------------------------
// K6: fused q/k/v/skip projection, panel-looped: A tile in LDS once, then
// 13 weight panels of 64 cols.  q panels pre-scaled by 0.125 (logit scale);
// k,v stored bf16; q,skip f32.
// ---------------------------------------------------------------------------
__global__ __launch_bounds__(256) void gemm_qkvs2(const float* __restrict__ A,
        const float* __restrict__ wq, const float* __restrict__ bq,
        const float* __restrict__ wk, const float* __restrict__ bk,
        const float* __restrict__ wv, const float* __restrict__ bv,
        const float* __restrict__ wsk, const float* __restrict__ bsk,
        float* __restrict__ qo, unsigned short* __restrict__ ko,
        unsigned short* __restrict__ vo, float* __restrict__ so, int n) {
    __shared__ float As[64][68];   // As[k][r]
    __shared__ float Bs[64][68];   // Bs[k][c]
    int row0 = blockIdx.x * 64;
    int tid = threadIdx.x;
    int r0 = (tid >> 4) * 4;
    int c0 = (tid & 15) * 4;

    #pragma unroll
    for (int it = 0; it < 4; ++it) {
        int r  = (tid >> 4) + it * 16;
        int c4 = (tid & 15) * 4;
        float4 val = make_float4(0.f, 0.f, 0.f, 0.f);
        if (row0 + r < n)
            val = *reinterpret_cast<const float4*>(A + (size_t)(row0 + r) * DIM + c4);
        As[c4 + 0][r] = val.x;
        As[c4 + 1][r] = val.y;
        As[c4 + 2][r] = val.z;
        As[c4 + 3][r] = val.w;
    }

    for (int p = 0; p < 13; ++p) {
        const float* W; const float* bias;
        float* outf = nullptr; unsigned short* outb = nullptr;
        int ncols, col0; float scale = 1.0f;
        if (p < 4)       { W = wq;  bias = bq;  outf = qo; ncols = HD; col0 = p * 64; scale = 0.125f; }
        else if (p < 8)  { W = wk;  bias = bk;  outb = ko; ncols = HD; col0 = (p - 4) * 64; }
        else if (p < 12) { W = wv;  bias = bv;  outb = vo; ncols = HD; col0 = (p - 8) * 64; }
        else             { W = wsk; bias = bsk; outf = so; ncols = DIM; col0 = 0; }

        #pragma unroll
        for (int it = 0; it < 4; ++it) {
            int r  = (tid >> 4) + it * 16;
            int c4 = (tid & 15) * 4;
            *reinterpret_cast<float4*>(&Bs[r][c4]) =
                *reinterpret_cast<const float4*>(W + (size_t)r * ncols + col0 + c4);
        }
        __syncthreads();

        float acc[4][4] = {};
        #pragma unroll 8
        for (int kk = 0; kk < 64; ++kk) {
            float4 av = *reinterpret_cast<const float4*>(&As[kk][r0]);
            float4 bv = *reinterpret_cast<const float4*>(&Bs[kk][c0]);
            float a_[4] = {av.x, av.y, av.z, av.w};
            float b_[4] = {bv.x, bv.y, bv.z, bv.w};
            #pragma unroll
            for (int i = 0; i < 4; ++i)
                #pragma unroll
                for (int j = 0; j < 4; ++j)
                    acc[i][j] += a_[i] * b_[j];
        }

        float b4[4] = { bias[col0 + c0 + 0], bias[col0 + c0 + 1],
                        bias[col0 + c0 + 2], bias[col0 + c0 + 3] };
        #pragma unroll
        for (int i = 0; i < 4; ++i) {
            int r = row0 + r0 + i;
            if (r >= n) continue;
            float4 o;
            o.x = (acc[i][0] + b4[0]) * scale;
            o.y = (acc[i][1] + b4[1]) * scale;
            o.z = (acc[i][2] + b4[2]) * scale;
            o.w = (acc[i][3] + b4[3]) * scale;
            if (outb) {
                ushort4 u;
                u.x = f2bf(o.x); u.y = f2bf(o.y); u.z = f2bf(o.z); u.w = f2bf(o.w);
                *reinterpret_cast<ushort4*>(outb + (size_t)r * ncols + col0 + c0) = u;
            } else {
                *reinterpret_cast<float4*>(outf + (size_t)r * ncols + col0 + c0) = o;
            }
        }
        __syncthreads();
    }
}

// ---------------------------------------------------------------------------
// K7: fused TransformerConv attention + beta gate.  One wave per node.
// lane = (head = lane>>4, 4-chan group = lane&15).  k,v bf16, q pre-scaled.
// 8-edge unroll: 16 gathers in flight.  Logits small -> no max-tracking.
// ---------------------------------------------------------------------------
__global__ __launch_bounds__(256) void attn_fused(const float* __restrict__ q,
                                                  const unsigned short* __restrict__ k,
                                                  const unsigned short* __restrict__ v,
                                                  const float* __restrict__ x_r,
                                                  const int* __restrict__ rowptr,
                                                  const int2* __restrict__ csr,
                                                  const float* __restrict__ wbeta,
                                                  float* __restrict__ f_tf, int n) {
    int wave = threadIdx.x >> 6;
    int lane = threadIdx.x & 63;
    int i = blockIdx.x * 4 + wave;
    if (i >= n) return;
    int h  = lane >> 4;
    int cg = lane & 15;
    int off = h * DIM + cg * 4;

    float4 q4 = *reinterpret_cast<const float4*>(q + (size_t)i * HD + off);
    float z = 0.f;
    float4 a = make_float4(0.f, 0.f, 0.f, 0.f);

    int e0 = rowptr[i], e1 = rowptr[i + 1];
    int e = e0;
    for (; e + 8 <= e1; e += 8) {
        int s[8];
        #pragma unroll
        for (int j = 0; j < 8; ++j) s[j] = csr[e + j].x;
        ushort4 kk[8], vv[8];
        #pragma unroll
        for (int j = 0; j < 8; ++j) {
            kk[j] = *reinterpret_cast<const ushort4*>(k + (size_t)s[j] * HD + off);
            vv[j] = *reinterpret_cast<const ushort4*>(v + (size_t)s[j] * HD + off);
        }
        float pl[8];
        #pragma unroll
        for (int j = 0; j < 8; ++j)
            pl[j] = q4.x * bf2f(kk[j].x) + q4.y * bf2f(kk[j].y)
                  + q4.z * bf2f(kk[j].z) + q4.w * bf2f(kk[j].w);
        #pragma unroll
        for (int j = 0; j < 8; ++j) pl[j] = reduce16(pl[j]);
        #pragma unroll
        for (int j = 0; j < 8; ++j) {
            float ez = __expf(pl[j]);
            z += ez;
            a.x += ez * bf2f(vv[j].x); a.y += ez * bf2f(vv[j].y);
            a.z += ez * bf2f(vv[j].z); a.w += ez * bf2f(vv[j].w);
        }
    }
    for (; e + 4 <= e1; e += 4) {
        int s[4];
        #pragma unroll
        for (int j = 0; j < 4; ++j) s[j] = csr[e + j].x;
        ushort4 kk[4], vv[4];
        #pragma unroll
        for (int j = 0; j < 4; ++j) {
            kk[j] = *reinterpret_cast<const ushort4*>(k + (size_t)s[j] * HD + off);
            vv[j] = *reinterpret_cast<const ushort4*>(v + (size_t)s[j] * HD + off);
        }
        float pl[4];
        #pragma unroll
        for (int j = 0; j < 4; ++j)
            pl[j] = q4.x * bf2f(kk[j].x) + q4.y * bf2f(kk[j].y)
                  + q4.z * bf2f(kk[j].z) + q4.w * bf2f(kk[j].w);
        #pragma unroll
        for (int j = 0; j < 4; ++j) pl[j] = reduce16(pl[j]);
        #pragma unroll
        for (int j = 0; j < 4; ++j) {
            float ez = __expf(pl[j]);
            z += ez;
            a.x += ez * bf2f(vv[j].x); a.y += ez * bf2f(vv[j].y);
            a.z += ez * bf2f(vv[j].z); a.w += ez * bf2f(vv[j].w);
        }
    }
    for (; e < e1; ++e) {
        int s = csr[e].x;
        ushort4 k4 = *reinterpret_cast<const ushort4*>(k + (size_t)s * HD + off);
        ushort4 v4 = *reinterpret_cast<const ushort4*>(v + (size_t)s * HD + off);
        float p = q4.x * bf2f(k4.x) + q4.y * bf2f(k4.y)
                + q4.z * bf2f(k4.z) + q4.w * bf2f(k4.w);
        p = reduce16(p);
        float ez = __expf(p);
        z += ez;
        a.x += ez * bf2f(v4.x); a.y += ez * bf2f(v4.y);
        a.z += ez * bf2f(v4.z); a.w += ez * bf2f(v4.w);
    }

    float inv = (e1 > e0) ? 1.0f / z : 0.f;
    float4 o;
    o.x = a.x * inv; o.y = a.y * inv; o.z = a.z * inv; o.w = a.w * inv;
    // mean over heads: sum across quarters, x0.25
    o.x += __shfl_xor(o.x, 16, 64); o.x += __shfl_xor(o.x, 32, 64);
    o.y += __shfl_xor(o.y, 16, 64); o.y += __shfl_xor(o.y, 32, 64);
    o.z += __shfl_xor(o.z, 16, 64); o.z += __shfl_xor(o.z, 32, 64);
    o.w += __shfl_xor(o.w, 16, 64); o.w += __shfl_xor(o.w, 32, 64);
    o.x *= 0.25f; o.y *= 0.25f; o.z *= 0.25f; o.w *= 0.25f;

    float4 xr4 = *reinterpret_cast<const float4*>(x_r + (size_t)i * DIM + cg * 4);
    const float* w1 = wbeta + cg * 4;
    const float* w2 = wbeta + 64 + cg * 4;
    const float* w3 = wbeta + 128 + cg * 4;
    float t = o.x * w1[0] + o.y * w1[1] + o.z * w1[2] + o.w * w1[3]
            + xr4.x * w2[0] + xr4.y * w2[1] + xr4.z * w2[2] + xr4.w * w2[3]
            + (o.x - xr4.x) * w3[0] + (o.y - xr4.y) * w3[1]
            + (o.z - xr4.z) * w3[2] + (o.w - xr4.w) * w3[3];
    t = reduce16(t);
    float beta = 1.0f / (1.0f + __expf(-t));
    float4 r;
    r.x = fmaxf(beta * xr4.x + (1.0f - beta) * o.x, 0.f);
    r.y = fmaxf(beta * xr4.y + (1.0f - beta) * o.y, 0.f);
    r.z = fmaxf(beta * xr4.z + (1.0f - beta) * o.z, 0.f);
    r.w = fmaxf(beta * xr4.w + (1.0f - beta) * o.w, 0.f);
    if (h == 0)
        *reinterpret_cast<float4*>(f_tf + (size_t)i * DIM + cg * 4) = r;
}

// ---------------------------------------------------------------------------
// K8: conv projection, o-major output:  out[o*N + n] = conv_w[o,:]·f_tf[n,:] + conv_b[o]
// ---------------------------------------------------------------------------
__global__ __launch_bounds__(256) void conv_out_k(const float* __restrict__ f_tf,
                                                  const float* __restrict__ conv_w,
                                                  const float* __restrict__ conv_b,
                                                  float* __restrict__ out, int n) {
    int nn = blockIdx.x * 256 + threadIdx.x;
    int ob = blockIdx.y * 16;
    if (nn >= n) return;
    float4 r4[16];
    #pragma unroll
    for (int j = 0; j < 16; ++j)
        r4[j] = *reinterpret_cast<const float4*>(f_tf + (size_t)nn * DIM + j * 4);
    #pragma unroll
    for (int oo = 0; oo < 16; ++oo) {
        int o = ob + oo;
        const float* wr = conv_w + (size_t)o * DIM;
        float acc = conv_b[o];
        #pragma unroll
        for (int j = 0; j < 16; ++j) {
            acc += r4[j].x * wr[j * 4 + 0] + r4[j].y * wr[j * 4 + 1] +
                   r4[j].z * wr[j * 4 + 2] + r4[j].w * wr[j * 4 + 3];
        }
        out[(size_t)o * n + nn] = acc;
    }
}

// ---------------------------------------------------------------------------
// launch
// ---------------------------------------------------------------------------
extern "C" void kernel_launch(void* const* d_in, const int* in_sizes, int n_in,
                              void* d_out, int out_size, void* d_ws, size_t ws_size,
                              hipStream_t stream) {
    const float* f_mole = (const float*)d_in[0];
    const float* edge_w = (const float*)d_in[1];
    const float* gcn_w  = (const float*)d_in[2];
    const float* gcn_b  = (const float*)d_in[3];
    const float* wq     = (const float*)d_in[4];
    const float* bq     = (const float*)d_in[5];
    const float* wk     = (const float*)d_in[6];
    const float* bk     = (const float*)d_in[7];
    const float* wv     = (const float*)d_in[8];
    const float* bv     = (const float*)d_in[9];
    const float* wskip  = (const float*)d_in[10];
    const float* bskip  = (const float*)d_in[11];
    const float* wbeta  = (const float*)d_in[12];
    const float* conv_w = (const float*)d_in[13];
    const float* conv_b = (const float*)d_in[14];
    const int*   edges  = (const int*)d_in[15];

    int N = in_sizes[0] / DIM;
    int E = in_sizes[1];

    float* ws = (float*)d_ws;
    size_t o = 0;
    int*   counts  = (int*)(ws + o); o += N;      // must stay first (memset)
    float* deg     = ws + o;         o += N;      // adjacent to counts (memset)
    float* dinv    = ws + o;         o += N;
    int*   cursor  = (int*)(ws + o); o += N;
    int*   rowptr  = (int*)(ws + o); o += (size_t)N + 4;
    int*   bsum    = (int*)(ws + o); o += 256;
    int2*  csr     = (int2*)(ws + o); o += (size_t)2 * E;
    unsigned short* xws = (unsigned short*)(ws + o); o += (size_t)N * DIM / 2;
    float* f_gcn   = ws + o;         o += (size_t)N * DIM;
    float* qb      = ws + o;         o += (size_t)N * HD;
    unsigned short* kb = (unsigned short*)(ws + o); o += (size_t)N * HD / 2;
    unsigned short* vb = (unsigned short*)(ws + o); o += (size_t)N * HD / 2;
    float* xrb     = ws + o;         o += (size_t)N * DIM;
    float* ftf     = ws + o;         o += (size_t)N * DIM;

    int ebl = (E + 255) / 256;
    int nbl = (N + 255) / 256;
    int gbl = (N + 63) / 64;

    hipMemsetAsync(d_ws, 0, (size_t)2 * N * sizeof(int), stream);
    edge_count<<<ebl, 256, 0, stream>>>(edges, edge_w, counts, deg, E);
    block_sums<<<nbl, 256, 0, stream>>>(counts, bsum, N);
    scan_apply<<<nbl, 256, 0, stream>>>(counts, bsum, deg, rowptr, cursor, dinv, N, E);
    edge_scatter<<<ebl, 256, 0, stream>>>(edges, edge_w, cursor, csr, E);

    gemm_xw<<<gbl, 256, 0, stream>>>(f_mole, gcn_w, dinv, xws, N);
    gcn_agg<<<(N + 3) / 4, 256, 0, stream>>>(xws, rowptr, csr, dinv, gcn_b, f_gcn, N);

    gemm_qkvs2<<<gbl, 256, 0, stream>>>(f_gcn, wq, bq, wk, bk, wv, bv,
                                        wskip, bskip, qb, kb, vb, xrb, N);

    attn_fused<<<(N + 3) / 4, 256, 0, stream>>>(qb, kb, vb, xrb, rowptr, csr, wbeta, ftf, N);
    conv_out_k<<<dim3(nbl, 4), 256, 0, stream>>>(ftf, conv_w, conv_b, (float*)d_out, N);
}

// Round 6
// 177.640 us; speedup vs baseline: 1.2132x; 1.2132x over previous
//
#include <hip/hip_runtime.h>
#include <hip/hip_bf16.h>

#define DIM 64
#define HEADS 4
#define HD 256   // HEADS*DIM
#define CAP 64   // padded CSR capacity per node

// ---------------------------------------------------------------------------
// helpers
// ---------------------------------------------------------------------------
template<int CTRL>
__device__ __forceinline__ float dpp_rot(float x) {
    return __int_as_float(__builtin_amdgcn_update_dpp(
        0, __float_as_int(x), CTRL, 0xF, 0xF, true));
}
// sum across each 16-lane row via rotational Hillis-Steele (pure VALU DPP)
__device__ __forceinline__ float reduce16(float x) {
    x += dpp_rot<0x121>(x);   // row_ror:1
    x += dpp_rot<0x122>(x);   // row_ror:2
    x += dpp_rot<0x124>(x);   // row_ror:4
    x += dpp_rot<0x128>(x);   // row_ror:8
    return x;
}
__device__ __forceinline__ unsigned short f2bf(float f) {
    unsigned u = __float_as_uint(f);
    unsigned r = (u + 0x7FFFu + ((u >> 16) & 1u)) >> 16;   // RNE
    return (unsigned short)r;
}
__device__ __forceinline__ float bf2f(unsigned short u) {
    return __uint_as_float((unsigned)u << 16);
}

// ---------------------------------------------------------------------------
// K1: one-pass CSR build into padded slots (counts/deg pre-zeroed by memset).
// csr[dst*CAP + slot] = (src, weight); deg[dst] += w.
// ---------------------------------------------------------------------------
__global__ void scatter_all(const int* __restrict__ edges, const float* __restrict__ ew,
                            int* counts, float* deg, int2* __restrict__ csr, int nE) {
    int e = blockIdx.x * blockDim.x + threadIdx.x;
    if (e < nE) {
        int dst = edges[nE + e];           // edges[1][e]
        int src = edges[e];
        float w = ew[e];
        int p = atomicAdd(&counts[dst], 1);
        int2 rec;
        rec.x = src;
        rec.y = __float_as_int(w);
        csr[(dst << 6) + p] = rec;
        atomicAdd(&deg[dst], w);
    }
}

// ---------------------------------------------------------------------------
// Shared GEMM tile helpers.  As is stored TRANSPOSED with an XOR swizzle on
// the row index: As[k][r ^ ((k>>2 & 7)<<2)] = A[row0+r][k].  The swizzle makes
// the 4-scalar transpose store 2-way-conflict (free) instead of 8-way, and
// reads stay contiguous float4 (r0 is 4-aligned, swizzle is 4-aligned).
// ---------------------------------------------------------------------------
__device__ __forceinline__ void tile_load_A(float (*As)[68], const float* __restrict__ A,
                                            int row0, int n, int tid) {
    int c4 = (tid & 15) * 4;
    int sw = (tid & 7) << 2;             // ((k>>2)&7)<<2 for k = c4..c4+3
    #pragma unroll
    for (int it = 0; it < 4; ++it) {
        int r = (tid >> 4) + it * 16;    // 0..63
        float4 val = make_float4(0.f, 0.f, 0.f, 0.f);
        if (row0 + r < n)
            val = *reinterpret_cast<const float4*>(A + (size_t)(row0 + r) * DIM + c4);
        int rs = r ^ sw;
        As[c4 + 0][rs] = val.x;
        As[c4 + 1][rs] = val.y;
        As[c4 + 2][rs] = val.z;
        As[c4 + 3][rs] = val.w;
    }
}

__device__ __forceinline__ void tile_mm(const float (*As)[68], const float (*Bs)[68],
                                        float acc[4][4], int r0, int c0) {
    #pragma unroll 8
    for (int kk = 0; kk < 64; ++kk) {
        int sw = ((kk >> 2) & 7) << 2;
        float4 av = *reinterpret_cast<const float4*>(&As[kk][r0 ^ sw]);
        float4 bv = *reinterpret_cast<const float4*>(&Bs[kk][c0]);
        float a_[4] = {av.x, av.y, av.z, av.w};
        float b_[4] = {bv.x, bv.y, bv.z, bv.w};
        #pragma unroll
        for (int i = 0; i < 4; ++i)
            #pragma unroll
            for (int j = 0; j < 4; ++j)
                acc[i][j] += a_[i] * b_[j];
    }
}

// ---------------------------------------------------------------------------
// K2: xws = dinv[row] * (f_mole @ gcn_w) in bf16; also computes dinv from deg.
// ---------------------------------------------------------------------------
__global__ __launch_bounds__(256) void gemm_xw(const float* __restrict__ A,
                                               const float* __restrict__ W,
                                               const float* __restrict__ deg,
                                               float* __restrict__ dinv,
                                               unsigned short* __restrict__ out,
                                               int n) {
    __shared__ float As[64][68];
    __shared__ float Bs[64][68];
    int row0 = blockIdx.x * 64;
    int tid = threadIdx.x;
    tile_load_A(As, A, row0, n, tid);
    #pragma unroll
    for (int it = 0; it < 4; ++it) {
        int r  = (tid >> 4) + it * 16;
        int c4 = (tid & 15) * 4;
        *reinterpret_cast<float4*>(&Bs[r][c4]) =
            *reinterpret_cast<const float4*>(W + (size_t)r * DIM + c4);
    }
    __syncthreads();
    int r0 = (tid >> 4) * 4;
    int c0 = (tid & 15) * 4;
    float acc[4][4] = {};
    tile_mm(As, Bs, acc, r0, c0);
    #pragma unroll
    for (int i = 0; i < 4; ++i) {
        int r = row0 + r0 + i;
        if (r >= n) continue;
        float d = rsqrtf(deg[r] + 1.0f);     // +1 = self-loop weight
        if (c0 == 0) dinv[r] = d;
        ushort4 u;
        u.x = f2bf(d * acc[i][0]); u.y = f2bf(d * acc[i][1]);
        u.z = f2bf(d * acc[i][2]); u.w = f2bf(d * acc[i][3]);
        *reinterpret_cast<ushort4*>(out + (size_t)r * DIM + c0) = u;
    }
}

// ---------------------------------------------------------------------------
// K3: GCN aggregation.  One wave per node; padded CSR.
// lane = (edge-slot = lane>>4, 4-chan group = lane&15); 16 edges in flight.
// f_gcn = relu( dinv[i]*(xws[i] + sum_e w*xws[src]) + b )
// ---------------------------------------------------------------------------
__global__ __launch_bounds__(256) void gcn_agg(const unsigned short* __restrict__ xws,
                                               const int* __restrict__ counts,
                                               const int2* __restrict__ csr,
                                               const float* __restrict__ dinv,
                                               const float* __restrict__ gcn_b,
                                               float* __restrict__ f_gcn, int n) {
    int wave = threadIdx.x >> 6;
    int lane = threadIdx.x & 63;
    int i = blockIdx.x * 4 + wave;
    if (i >= n) return;
    int eo = lane >> 4;
    int cg = lane & 15;

    float4 acc = make_float4(0.f, 0.f, 0.f, 0.f);
    int e0 = i << 6;
    int e1 = e0 + counts[i];
    int eb = e0;
    for (; eb + 16 <= e1; eb += 16) {
        int2 p[4];
        #pragma unroll
        for (int j = 0; j < 4; ++j) p[j] = csr[eb + 4 * j + eo];
        ushort4 x[4];
        #pragma unroll
        for (int j = 0; j < 4; ++j)
            x[j] = *reinterpret_cast<const ushort4*>(xws + (size_t)p[j].x * DIM + cg * 4);
        #pragma unroll
        for (int j = 0; j < 4; ++j) {
            float c = __int_as_float(p[j].y);
            acc.x += c * bf2f(x[j].x); acc.y += c * bf2f(x[j].y);
            acc.z += c * bf2f(x[j].z); acc.w += c * bf2f(x[j].w);
        }
    }
    for (int e = eb + eo; e < e1; e += 4) {
        int2 p = csr[e];
        float c = __int_as_float(p.y);
        ushort4 x4 = *reinterpret_cast<const ushort4*>(xws + (size_t)p.x * DIM + cg * 4);
        acc.x += c * bf2f(x4.x); acc.y += c * bf2f(x4.y);
        acc.z += c * bf2f(x4.z); acc.w += c * bf2f(x4.w);
    }
    // sum the 4 edge-slots (cross-quarter)
    acc.x += __shfl_xor(acc.x, 16, 64); acc.x += __shfl_xor(acc.x, 32, 64);
    acc.y += __shfl_xor(acc.y, 16, 64); acc.y += __shfl_xor(acc.y, 32, 64);
    acc.z += __shfl_xor(acc.z, 16, 64); acc.z += __shfl_xor(acc.z, 32, 64);
    acc.w += __shfl_xor(acc.w, 16, 64); acc.w += __shfl_xor(acc.w, 32, 64);

    float di = dinv[i];
    ushort4 xs = *reinterpret_cast<const ushort4*>(xws + (size_t)i * DIM + cg * 4);
    const float* b = gcn_b + cg * 4;
    float4 r;
    r.x = fmaxf(di * (acc.x + bf2f(xs.x)) + b[0], 0.f);
    r.y = fmaxf(di * (acc.y + bf2f(xs.y)) + b[1], 0.f);
    r.z = fmaxf(di * (acc.z + bf2f(xs.z)) + b[2], 0.f);
    r.w = fmaxf(di * (acc.w + bf2f(xs.w)) + b[3], 0.f);
    if (eo == 0)
        *reinterpret_cast<float4*>(f_gcn + (size_t)i * DIM + cg * 4) = r;
}

// ---------------------------------------------------------------------------
// K4: fused q/k/v/skip projection, 2D grid (row-tile x 13 panels).
// q pre-scaled by 0.125 (logit scale); k,v stored bf16; q,skip f32.
// ---------------------------------------------------------------------------
__global__ __launch_bounds__(256) void gemm_qkvs(const float* __restrict__ A,
        const float* __restrict__ wq, const float* __restrict__ bq,
        const float* __restrict__ wk, const float* __restrict__ bk,
        const float* __restrict__ wv, const float* __restrict__ bv,
        const float* __restrict__ wsk, const float* __restrict__ bsk,
        float* __restrict__ qo, unsigned short* __restrict__ ko,
        unsigned short* __restrict__ vo, float* __restrict__ so, int n) {
    __shared__ float As[64][68];
    __shared__ float Bs[64][68];
    int ty = blockIdx.y;
    const float* W; const float* bias;
    float* outf = nullptr; unsigned short* outb = nullptr;
    int ncols, col0; float scale = 1.0f;
    if (ty < 4)       { W = wq;  bias = bq;  outf = qo; ncols = HD; col0 = ty * 64; scale = 0.125f; }
    else if (ty < 8)  { W = wk;  bias = bk;  outb = ko; ncols = HD; col0 = (ty - 4) * 64; }
    else if (ty < 12) { W = wv;  bias = bv;  outb = vo; ncols = HD; col0 = (ty - 8) * 64; }
    else              { W = wsk; bias = bsk; outf = so; ncols = DIM; col0 = 0; }

    int row0 = blockIdx.x * 64;
    int tid = threadIdx.x;
    tile_load_A(As, A, row0, n, tid);
    #pragma unroll
    for (int it = 0; it < 4; ++it) {
        int r  = (tid >> 4) + it * 16;
        int c4 = (tid & 15) * 4;
        *reinterpret_cast<float4*>(&Bs[r][c4]) =
            *reinterpret_cast<const float4*>(W + (size_t)r * ncols + col0 + c4);
    }
    __syncthreads();

    int r0 = (tid >> 4) * 4;
    int c0 = (tid & 15) * 4;
    float acc[4][4] = {};
    tile_mm(As, Bs, acc, r0, c0);

    float b4[4] = { bias[col0 + c0 + 0], bias[col0 + c0 + 1],
                    bias[col0 + c0 + 2], bias[col0 + c0 + 3] };
    #pragma unroll
    for (int i = 0; i < 4; ++i) {
        int r = row0 + r0 + i;
        if (r >= n) continue;
        float4 o;
        o.x = (acc[i][0] + b4[0]) * scale;
        o.y = (acc[i][1] + b4[1]) * scale;
        o.z = (acc[i][2] + b4[2]) * scale;
        o.w = (acc[i][3] + b4[3]) * scale;
        if (outb) {
            ushort4 u;
            u.x = f2bf(o.x); u.y = f2bf(o.y); u.z = f2bf(o.z); u.w = f2bf(o.w);
            *reinterpret_cast<ushort4*>(outb + (size_t)r * ncols + col0 + c0) = u;
        } else {
            *reinterpret_cast<float4*>(outf + (size_t)r * ncols + col0 + c0) = o;
        }
    }
}

// ---------------------------------------------------------------------------
// K5: fused TransformerConv attention + beta gate.  One wave per node.
// lane = (head = lane>>4, 4-chan group = lane&15).  k,v bf16, q pre-scaled.
// 8-edge unroll: 16 gathers in flight.  Logits small -> no max-tracking.
// ---------------------------------------------------------------------------
__global__ __launch_bounds__(256) void attn_fused(const float* __restrict__ q,
                                                  const unsigned short* __restrict__ k,
                                                  const unsigned short* __restrict__ v,
                                                  const float* __restrict__ x_r,
                                                  const int* __restrict__ counts,
                                                  const int2* __restrict__ csr,
                                                  const float* __restrict__ wbeta,
                                                  float* __restrict__ f_tf, int n) {
    int wave = threadIdx.x >> 6;
    int lane = threadIdx.x & 63;
    int i = blockIdx.x * 4 + wave;
    if (i >= n) return;
    int h  = lane >> 4;
    int cg = lane & 15;
    int off = h * DIM + cg * 4;

    float4 q4 = *reinterpret_cast<const float4*>(q + (size_t)i * HD + off);
    float z = 0.f;
    float4 a = make_float4(0.f, 0.f, 0.f, 0.f);

    int e0 = i << 6;
    int cnt = counts[i];
    int e1 = e0 + cnt;
    int e = e0;
    for (; e + 8 <= e1; e += 8) {
        int s[8];
        #pragma unroll
        for (int j = 0; j < 8; ++j) s[j] = csr[e + j].x;
        ushort4 kk[8], vv[8];
        #pragma unroll
        for (int j = 0; j < 8; ++j) {
            kk[j] = *reinterpret_cast<const ushort4*>(k + (size_t)s[j] * HD + off);
            vv[j] = *reinterpret_cast<const ushort4*>(v + (size_t)s[j] * HD + off);
        }
        float pl[8];
        #pragma unroll
        for (int j = 0; j < 8; ++j)
            pl[j] = q4.x * bf2f(kk[j].x) + q4.y * bf2f(kk[j].y)
                  + q4.z * bf2f(kk[j].z) + q4.w * bf2f(kk[j].w);
        #pragma unroll
        for (int j = 0; j < 8; ++j) pl[j] = reduce16(pl[j]);
        #pragma unroll
        for (int j = 0; j < 8; ++j) {
            float ez = __expf(pl[j]);
            z += ez;
            a.x += ez * bf2f(vv[j].x); a.y += ez * bf2f(vv[j].y);
            a.z += ez * bf2f(vv[j].z); a.w += ez * bf2f(vv[j].w);
        }
    }
    for (; e + 4 <= e1; e += 4) {
        int s[4];
        #pragma unroll
        for (int j = 0; j < 4; ++j) s[j] = csr[e + j].x;
        ushort4 kk[4], vv[4];
        #pragma unroll
        for (int j = 0; j < 4; ++j) {
            kk[j] = *reinterpret_cast<const ushort4*>(k + (size_t)s[j] * HD + off);
            vv[j] = *reinterpret_cast<const ushort4*>(v + (size_t)s[j] * HD + off);
        }
        float pl[4];
        #pragma unroll
        for (int j = 0; j < 4; ++j)
            pl[j] = q4.x * bf2f(kk[j].x) + q4.y * bf2f(kk[j].y)
                  + q4.z * bf2f(kk[j].z) + q4.w * bf2f(kk[j].w);
        #pragma unroll
        for (int j = 0; j < 4; ++j) pl[j] = reduce16(pl[j]);
        #pragma unroll
        for (int j = 0; j < 4; ++j) {
            float ez = __expf(pl[j]);
            z += ez;
            a.x += ez * bf2f(vv[j].x); a.y += ez * bf2f(vv[j].y);
            a.z += ez * bf2f(vv[j].z); a.w += ez * bf2f(vv[j].w);
        }
    }
    for (; e < e1; ++e) {
        int s = csr[e].x;
        ushort4 k4 = *reinterpret_cast<const ushort4*>(k + (size_t)s * HD + off);
        ushort4 v4 = *reinterpret_cast<const ushort4*>(v + (size_t)s * HD + off);
        float p = q4.x * bf2f(k4.x) + q4.y * bf2f(k4.y)
                + q4.z * bf2f(k4.z) + q4.w * bf2f(k4.w);
        p = reduce16(p);
        float ez = __expf(p);
        z += ez;
        a.x += ez * bf2f(v4.x); a.y += ez * bf2f(v4.y);
        a.z += ez * bf2f(v4.z); a.w += ez * bf2f(v4.w);
    }

    float inv = (cnt > 0) ? 1.0f / z : 0.f;
    float4 o;
    o.x = a.x * inv; o.y = a.y * inv; o.z = a.z * inv; o.w = a.w * inv;
    // mean over heads: sum across quarters, x0.25
    o.x += __shfl_xor(o.x, 16, 64); o.x += __shfl_xor(o.x, 32, 64);
    o.y += __shfl_xor(o.y, 16, 64); o.y += __shfl_xor(o.y, 32, 64);
    o.z += __shfl_xor(o.z, 16, 64); o.z += __shfl_xor(o.z, 32, 64);
    o.w += __shfl_xor(o.w, 16, 64); o.w += __shfl_xor(o.w, 32, 64);
    o.x *= 0.25f; o.y *= 0.25f; o.z *= 0.25f; o.w *= 0.25f;

    float4 xr4 = *reinterpret_cast<const float4*>(x_r + (size_t)i * DIM + cg * 4);
    const float* w1 = wbeta + cg * 4;
    const float* w2 = wbeta + 64 + cg * 4;
    const float* w3 = wbeta + 128 + cg * 4;
    float t = o.x * w1[0] + o.y * w1[1] + o.z * w1[2] + o.w * w1[3]
            + xr4.x * w2[0] + xr4.y * w2[1] + xr4.z * w2[2] + xr4.w * w2[3]
            + (o.x - xr4.x) * w3[0] + (o.y - xr4.y) * w3[1]
            + (o.z - xr4.z) * w3[2] + (o.w - xr4.w) * w3[3];
    t = reduce16(t);
    float beta = 1.0f / (1.0f + __expf(-t));
    float4 r;
    r.x = fmaxf(beta * xr4.x + (1.0f - beta) * o.x, 0.f);
    r.y = fmaxf(beta * xr4.y + (1.0f - beta) * o.y, 0.f);
    r.z = fmaxf(beta * xr4.z + (1.0f - beta) * o.z, 0.f);
    r.w = fmaxf(beta * xr4.w + (1.0f - beta) * o.w, 0.f);
    if (h == 0)
        *reinterpret_cast<float4*>(f_tf + (size_t)i * DIM + cg * 4) = r;
}

// ---------------------------------------------------------------------------
// K6: conv projection, o-major output:  out[o*N + n] = conv_w[o,:]·f_tf[n,:] + conv_b[o]
// single pass over f_tf: 64 outputs per thread.
// ---------------------------------------------------------------------------
__global__ __launch_bounds__(256) void conv_out_k(const float* __restrict__ f_tf,
                                                  const float* __restrict__ conv_w,
                                                  const float* __restrict__ conv_b,
                                                  float* __restrict__ out, int n) {
    int nn = blockIdx.x * 256 + threadIdx.x;
    if (nn >= n) return;
    float4 r4[16];
    #pragma unroll
    for (int j = 0; j < 16; ++j)
        r4[j] = *reinterpret_cast<const float4*>(f_tf + (size_t)nn * DIM + j * 4);
    for (int o = 0; o < 64; ++o) {
        const float* wr = conv_w + (size_t)o * DIM;
        float acc = conv_b[o];
        #pragma unroll
        for (int j = 0; j < 16; ++j) {
            acc += r4[j].x * wr[j * 4 + 0] + r4[j].y * wr[j * 4 + 1] +
                   r4[j].z * wr[j * 4 + 2] + r4[j].w * wr[j * 4 + 3];
        }
        out[(size_t)o * n + nn] = acc;
    }
}

// ---------------------------------------------------------------------------
// launch
// ---------------------------------------------------------------------------
extern "C" void kernel_launch(void* const* d_in, const int* in_sizes, int n_in,
                              void* d_out, int out_size, void* d_ws, size_t ws_size,
                              hipStream_t stream) {
    const float* f_mole = (const float*)d_in[0];
    const float* edge_w = (const float*)d_in[1];
    const float* gcn_w  = (const float*)d_in[2];
    const float* gcn_b  = (const float*)d_in[3];
    const float* wq     = (const float*)d_in[4];
    const float* bq     = (const float*)d_in[5];
    const float* wk     = (const float*)d_in[6];
    const float* bk     = (const float*)d_in[7];
    const float* wv     = (const float*)d_in[8];
    const float* bv     = (const float*)d_in[9];
    const float* wskip  = (const float*)d_in[10];
    const float* bskip  = (const float*)d_in[11];
    const float* wbeta  = (const float*)d_in[12];
    const float* conv_w = (const float*)d_in[13];
    const float* conv_b = (const float*)d_in[14];
    const int*   edges  = (const int*)d_in[15];

    int N = in_sizes[0] / DIM;
    int E = in_sizes[1];

    float* ws = (float*)d_ws;
    size_t o = 0;
    int*   counts  = (int*)(ws + o); o += N;      // must stay first (memset)
    float* deg     = ws + o;         o += N;      // adjacent to counts (memset)
    float* dinv    = ws + o;         o += N;
    int2*  csr     = (int2*)(ws + o); o += (size_t)2 * N * CAP;
    unsigned short* xws = (unsigned short*)(ws + o); o += (size_t)N * DIM / 2;
    float* f_gcn   = ws + o;         o += (size_t)N * DIM;
    float* qb      = ws + o;         o += (size_t)N * HD;
    unsigned short* kb = (unsigned short*)(ws + o); o += (size_t)N * HD / 2;
    unsigned short* vb = (unsigned short*)(ws + o); o += (size_t)N * HD / 2;
    float* xrb     = ws + o;         o += (size_t)N * DIM;
    float* ftf     = ws + o;         o += (size_t)N * DIM;

    int ebl = (E + 255) / 256;
    int nbl = (N + 255) / 256;
    int gbl = (N + 63) / 64;

    hipMemsetAsync(d_ws, 0, (size_t)2 * N * sizeof(int), stream);
    scatter_all<<<ebl, 256, 0, stream>>>(edges, edge_w, counts, deg, csr, E);

    gemm_xw<<<gbl, 256, 0, stream>>>(f_mole, gcn_w, deg, dinv, xws, N);
    gcn_agg<<<(N + 3) / 4, 256, 0, stream>>>(xws, counts, csr, dinv, gcn_b, f_gcn, N);

    gemm_qkvs<<<dim3(gbl, 13), 256, 0, stream>>>(f_gcn, wq, bq, wk, bk, wv, bv,
                                                 wskip, bskip, qb, kb, vb, xrb, N);

    attn_fused<<<(N + 3) / 4, 256, 0, stream>>>(qb, kb, vb, xrb, counts, csr, wbeta, ftf, N);
    conv_out_k<<<nbl, 256, 0, stream>>>(ftf, conv_w, conv_b, (float*)d_out, N);
}